// Round 16
// baseline (181.055 us; speedup 1.0000x reference)
//
#include <hip/hip_runtime.h>
#include <hip/hip_bf16.h>
#include <math.h>

// Bidirectional Mamba block. Round 16: persistent m-loop GEMM — each block
// streams MLOOP m-tiles through ONE seamless double-buffered pipeline
// (prefetch crosses m-tile boundaries; pipeline warms once per block, not
// once per 4-16-step tile). Inner structure = r10 verbatim. Rest = r15.

#define NTOK 8192
#define LL   2048
#define DM   256
#define DI   512
#define DS2  16
#define CL   64
#define NCH  32
#define PLANE 65536
#define KSTEP 64

typedef __bf16 bf16x8 __attribute__((ext_vector_type(8)));
typedef float f32x4 __attribute__((ext_vector_type(4)));

__device__ inline unsigned short f2bf(float f) {
    unsigned u = __float_as_uint(f);
    unsigned r = (u + 0x7fffu + ((u >> 16) & 1u)) >> 16;
    return (unsigned short)r;
}
__device__ inline float bf2f(unsigned short s) {
    return __uint_as_float((unsigned)s << 16);
}

#define L2E 1.4426950408889634f
#define LN2 0.6931471805599453f

__device__ inline float softplus_fast(float x) {
    float e = __builtin_amdgcn_exp2f(-fabsf(x) * L2E);
    float l = __builtin_amdgcn_logf(1.f + e);
    return fmaxf(x, 0.f) + l * LN2;
}

// bijective XCD-chunk swizzle (m204)
__device__ inline int xcd_swz(int bid, int nwg) {
    int q = nwg >> 3, r = nwg & 7;
    int xcd = bid & 7, lo = bid >> 3;
    return (xcd < r ? xcd * (q + 1) : r * (q + 1) + (xcd - r) * q) + lo;
}

#define GLDS(gp, lp) __builtin_amdgcn_global_load_lds( \
    (const __attribute__((address_space(1))) void*)(gp), \
    (__attribute__((address_space(3))) void*)(lp), 16, 0, 0)

// ---------------- prep: weight conversion / folding + rmsnorm -------------
__global__ __launch_bounds__(256) void prep_kernel(
    const float* __restrict__ ip0, const float* __restrict__ nw0,
    const float* __restrict__ ip1, const float* __restrict__ nw1,
    const float* __restrict__ xp0, const float* __restrict__ dtw0,
    const float* __restrict__ xp1, const float* __restrict__ dtw1,
    const float* __restrict__ op0, const float* __restrict__ op1,
    unsigned short* __restrict__ w_in, unsigned short* __restrict__ w_p2,
    unsigned short* __restrict__ w_out,
    const float* __restrict__ x, unsigned short* __restrict__ xn) {
    int bid = blockIdx.x, tid = threadIdx.x;
    if (bid < 2048) {                       // in_proj rows, norm folded
        int dir = bid >> 10, n = bid & 1023;
        const float* ip = dir ? ip1 : ip0;
        const float* nw = dir ? nw1 : nw0;
        w_in[(size_t)bid * 256 + tid] = f2bf(ip[n * 256 + tid] * nw[tid]);
    } else if (bid < 3200) {                // w_p2 rows (576 per dir)
        int idx = bid - 2048;
        int dir = idx / 576, row = idx % 576;
        const float* xp = dir ? xp1 : xp0;
        const float* dtw = dir ? dtw1 : dtw0;
        unsigned short* dst = w_p2 + (size_t)idx * 512;
        for (int k = tid; k < 512; k += 256) {
            float v = 0.f;
            if (row < 512) {
                #pragma unroll
                for (int r = 0; r < 16; ++r) v = fmaf(dtw[row * 16 + r], xp[r * 512 + k], v);
            } else if (row < 544) {
                v = xp[(16 + row - 512) * 512 + k];
            }
            dst[k] = f2bf(v);
        }
    } else if (bid < 3456) {                // w_out rows (256), K=1024 concat
        int n = bid - 3200;
        for (int k = tid; k < 1024; k += 256) {
            float v = (k < 512) ? op0[n * 512 + k] : op1[n * 512 + (k - 512)];
            w_out[(size_t)n * 1024 + k] = f2bf(v);
        }
    } else {                                // rmsnorm token
        int t = bid - 3456;
        float v = x[(size_t)t * DM + tid];
        float ss = v * v;
        #pragma unroll
        for (int m = 1; m < 64; m <<= 1) ss += __shfl_xor(ss, m);
        __shared__ float ws[4];
        if ((tid & 63) == 0) ws[tid >> 6] = ss;
        __syncthreads();
        float tot = ws[0] + ws[1] + ws[2] + ws[3];
        float scale = rsqrtf(tot / (float)DM + 1e-5f);
        xn[(size_t)t * DM + tid] = f2bf(v * scale);
    }
}

// ---------------- bf16 MFMA GEMM with persistent m-loop -------------------
#define EPI_IN  0   // -> xzcat[m][n], n in [0,2048)
#define EPI_P2  1
#define EPI_OUT 2

template <int EPI, int K, int MLOOP>
__global__ __launch_bounds__(256) void mfma_gemm(
    const unsigned short* __restrict__ A0, const unsigned short* __restrict__ A1,
    const unsigned short* __restrict__ Wb,
    unsigned short* __restrict__ d0, unsigned short* __restrict__ d1,
    unsigned short* __restrict__ e0, unsigned short* __restrict__ e1,
    const float* __restrict__ aux0, const float* __restrict__ aux1,
    const float* __restrict__ Xres, float* __restrict__ outF) {
    __shared__ char lds[2][2][8192];     // [buf][A/B][64 rows * 128B]
    int tid = threadIdx.x;
    int lane = tid & 63, wid = tid >> 6;
    int wm = wid >> 1, wn = wid & 1;
    int nwg = gridDim.x * gridDim.y;
    int lid = xcd_swz(blockIdx.y * gridDim.x + blockIdx.x, nwg);
    int n0 = (lid % gridDim.x) * 64;
    int mbase = (lid / gridDim.x) * (MLOOP * 64);
    int dir = blockIdx.z;
    const unsigned short* A = dir ? A1 : A0;
    const unsigned short* W = Wb + ((EPI == EPI_P2) ? (size_t)dir * 576 * 512 : 0);

    const int s1 = tid, s2 = tid + 256;
    const int r1 = s1 >> 3, c1 = (s1 & 7) ^ (r1 & 7);
    const int r2 = s2 >> 3, c2 = (s2 & 7) ^ (r2 & 7);

    constexpr int nt = K / KSTEP;
    constexpr int total = MLOOP * nt;

    f32x4 acc[2][2] = {};

    auto stage = [&](int it, int buf) {
        int mi = it / nt, t = it % nt;
        int m0 = mbase + mi * 64;
        int k0 = t * KSTEP;
        GLDS(A + (size_t)(m0 + r1) * K + k0 + c1 * 8, &lds[buf][0][0] + wid * 1024);
        GLDS(A + (size_t)(m0 + r2) * K + k0 + c2 * 8, &lds[buf][0][0] + 4096 + wid * 1024);
        GLDS(W + (size_t)(n0 + r1) * K + k0 + c1 * 8, &lds[buf][1][0] + wid * 1024);
        GLDS(W + (size_t)(n0 + r2) * K + k0 + c2 * 8, &lds[buf][1][0] + 4096 + wid * 1024);
    };

    stage(0, 0);
    for (int it = 0; it < total; ++it) {
        int buf = it & 1;
        __syncthreads();                 // prev reads done + this buf's loads drained
        if (it + 1 < total) stage(it + 1, buf ^ 1);
        const char* Ab = &lds[buf][0][0];
        const char* Bb = &lds[buf][1][0];
        bf16x8 af[2][2], bfv[2][2];
        #pragma unroll
        for (int mf = 0; mf < 2; ++mf)
            #pragma unroll
            for (int kf = 0; kf < 2; ++kf) {
                int r = wm * 32 + mf * 16 + (lane & 15);
                int c = (lane >> 4) + kf * 4;
                af[mf][kf] = *(const bf16x8*)(Ab + r * 128 + ((c ^ (r & 7)) << 4));
            }
        #pragma unroll
        for (int nf = 0; nf < 2; ++nf)
            #pragma unroll
            for (int kf = 0; kf < 2; ++kf) {
                int r = wn * 32 + nf * 16 + (lane & 15);
                int c = (lane >> 4) + kf * 4;
                bfv[nf][kf] = *(const bf16x8*)(Bb + r * 128 + ((c ^ (r & 7)) << 4));
            }
        #pragma unroll
        for (int kf = 0; kf < 2; ++kf)
            #pragma unroll
            for (int mf = 0; mf < 2; ++mf)
                #pragma unroll
                for (int nf = 0; nf < 2; ++nf)
                    acc[mf][nf] = __builtin_amdgcn_mfma_f32_16x16x32_bf16(
                        af[mf][kf], bfv[nf][kf], acc[mf][nf], 0, 0, 0);

        if ((it % nt) == nt - 1) {       // tile finished: epilogue + reset
            int m0 = mbase + (it / nt) * 64;
            int cb0 = n0 + wn * 32 + (lane & 15);
            int rb0 = m0 + wm * 32 + ((lane >> 4) << 2);
            #pragma unroll
            for (int mf = 0; mf < 2; ++mf)
                #pragma unroll
                for (int nf = 0; nf < 2; ++nf) {
                    int n = cb0 + nf * 16;
                    #pragma unroll
                    for (int r = 0; r < 4; ++r) {
                        int m = rb0 + mf * 16 + r;
                        float v = acc[mf][nf][r];
                        if (EPI == EPI_IN) {
                            d0[(size_t)m * 2048 + n] = f2bf(v);   // xzcat
                        } else if (EPI == EPI_P2) {
                            if (n < 512) {
                                float sv = v + (dir ? aux1 : aux0)[n];
                                (dir ? d1 : d0)[(size_t)m * 512 + n] = f2bf(softplus_fast(sv));
                            } else if (n < 544) {
                                (dir ? e1 : e0)[(size_t)m * 32 + (n - 512)] = f2bf(v);
                            }
                        } else {
                            outF[(size_t)m * 256 + n] = v + 2.f * Xres[(size_t)m * 256 + n];
                        }
                    }
                }
            f32x4 z4 = {0.f, 0.f, 0.f, 0.f};
            #pragma unroll
            for (int mf = 0; mf < 2; ++mf)
                #pragma unroll
                for (int nf = 0; nf < 2; ++nf)
                    acc[mf][nf] = z4;
        }
    }
}

// ---------------- depthwise conv4 + silu (bf16, 8 ch/thread) --------------
__global__ __launch_bounds__(256) void conv_silu_kernel(
    const unsigned short* __restrict__ xz,
    const float* __restrict__ cw0, const float* __restrict__ cw1,
    const float* __restrict__ cb0, const float* __restrict__ cb1,
    unsigned short* __restrict__ o0, unsigned short* __restrict__ o1) {
    int dir = blockIdx.y;
    const float* cw = dir ? cw1 : cw0;
    const float* cb = dir ? cb1 : cb0;
    unsigned short* xc = dir ? o1 : o0;
    int idx8 = blockIdx.x * 256 + threadIdx.x;
    int t = idx8 >> 6;
    int c8 = (idx8 & 63) << 3;
    int l = t & (LL - 1);
    const unsigned short* xh = xz + (size_t)dir * 1024 + c8;

    float wreg[32];
    #pragma unroll
    for (int q = 0; q < 8; ++q)
        *(float4*)&wreg[q * 4] = *(const float4*)&cw[c8 * 4 + q * 4];
    float acc[8];
    *(float4*)&acc[0] = *(const float4*)&cb[c8];
    *(float4*)&acc[4] = *(const float4*)&cb[c8 + 4];

    #pragma unroll
    for (int k = 0; k < 4; ++k) {
        int lo = dir ? (l + 3 - k) : (l - 3 + k);
        if (lo < 0 || lo >= LL) continue;
        uint4 u = *(const uint4*)(xh + (size_t)(t + lo - l) * 2048);
        unsigned wv[4] = {u.x, u.y, u.z, u.w};
        #pragma unroll
        for (int j = 0; j < 4; ++j) {
            float flo = __uint_as_float(wv[j] << 16);
            float fhi = __uint_as_float(wv[j] & 0xffff0000u);
            acc[2 * j]     = fmaf(flo, wreg[(2 * j) * 4 + k], acc[2 * j]);
            acc[2 * j + 1] = fmaf(fhi, wreg[(2 * j + 1) * 4 + k], acc[2 * j + 1]);
        }
    }
    unsigned out[4];
    #pragma unroll
    for (int j = 0; j < 4; ++j) {
        float a0 = acc[2 * j], a1 = acc[2 * j + 1];
        float s0 = a0 / (1.f + __expf(-a0));
        float s1 = a1 / (1.f + __expf(-a1));
        out[j] = (unsigned)f2bf(s0) | ((unsigned)f2bf(s1) << 16);
    }
    *(uint4*)(xc + (size_t)idx8 * 8) = make_uint4(out[0], out[1], out[2], out[3]);
}

// ---------------- scan part1: local chunk scan -> AC, HC, (y_loc,s) -------
// 128 threads, each owns one d with all 16 n-states (no shuffle). (r15)
__global__ __launch_bounds__(128, 2) void scan_part1(
    const unsigned short* __restrict__ dlt0, const unsigned short* __restrict__ dlt1,
    const unsigned short* __restrict__ xc0, const unsigned short* __restrict__ xc1,
    const unsigned short* __restrict__ bc0, const unsigned short* __restrict__ bc1,
    const float* __restrict__ Al0, const float* __restrict__ Al1,
    const float* __restrict__ Dp0, const float* __restrict__ Dp1,
    float* __restrict__ AC, float* __restrict__ HC,
    unsigned* __restrict__ yls0, unsigned* __restrict__ yls1) {
    int dir = blockIdx.z;
    const unsigned short* delta = dir ? dlt1 : dlt0;
    const unsigned short* xc    = dir ? xc1 : xc0;
    const unsigned short* bc    = dir ? bc1 : bc0;
    const float* Alog           = dir ? Al1 : Al0;
    const float* Dp             = dir ? Dp1 : Dp0;
    unsigned* yls               = dir ? yls1 : yls0;
    int b = blockIdx.y >> 5, ch = blockIdx.y & 31;
    int d0 = blockIdx.x * 128;
    int tid = threadIdx.x;               // 0..127 == local d
    int d = d0 + tid;

    __shared__ unsigned sdxu[CL][128];   // [l][d] packed (delta|xc), col XOR row
    __shared__ float sB[CL][16];         // [l][n] f32
    __shared__ float sC[CL][16];
    {
        int row = tid >> 1, q2 = tid & 1;
        int lr = ch * CL + row;
        int l = dir ? (LL - 1 - lr) : lr;
        size_t t = (size_t)b * LL + l;
        const uint4* dp = (const uint4*)(delta + t * DI + d0) + q2 * 8;
        const uint4* xp = (const uint4*)(xc + t * DI + d0) + q2 * 8;
        #pragma unroll
        for (int hh = 0; hh < 8; ++hh) {
            uint4 du = dp[hh], xu = xp[hh];
            unsigned dw[4] = {du.x, du.y, du.z, du.w};
            unsigned xw[4] = {xu.x, xu.y, xu.z, xu.w};
            #pragma unroll
            for (int j = 0; j < 4; ++j) {
                int col = q2 * 64 + hh * 8 + 2 * j;
                sdxu[row][col ^ row]       = (dw[j] & 0xffffu) | (xw[j] << 16);
                sdxu[row][(col + 1) ^ row] = (dw[j] >> 16) | (xw[j] & 0xffff0000u);
            }
        }
        uint4 Bu = *(const uint4*)(bc + t * 32 + q2 * 8);
        uint4 Cu = *(const uint4*)(bc + t * 32 + 16 + q2 * 8);
        unsigned bw[4] = {Bu.x, Bu.y, Bu.z, Bu.w};
        unsigned cw[4] = {Cu.x, Cu.y, Cu.z, Cu.w};
        #pragma unroll
        for (int j = 0; j < 4; ++j) {
            sB[row][q2 * 8 + 2 * j]     = __uint_as_float(bw[j] << 16);
            sB[row][q2 * 8 + 2 * j + 1] = __uint_as_float(bw[j] & 0xffff0000u);
            sC[row][q2 * 8 + 2 * j]     = __uint_as_float(cw[j] << 16);
            sC[row][q2 * 8 + 2 * j + 1] = __uint_as_float(cw[j] & 0xffff0000u);
        }
    }
    __syncthreads();

    float Av[16], Avl[16];
    #pragma unroll
    for (int qq = 0; qq < 4; ++qq) {
        float4 Al = *(const float4*)&Alog[d * DS2 + qq * 4];
        Av[qq * 4 + 0] = -__expf(Al.x);
        Av[qq * 4 + 1] = -__expf(Al.y);
        Av[qq * 4 + 2] = -__expf(Al.z);
        Av[qq * 4 + 3] = -__expf(Al.w);
    }
    #pragma unroll
    for (int j = 0; j < 16; ++j) Avl[j] = Av[j] * L2E;
    bool fast = true;
    #pragma unroll
    for (int j = 0; j < 15; ++j)
        fast = fast && (fabsf(Av[j + 1] - Av[j] + 1.f) < 1e-2f);

    float Dv = Dp[d];
    float h[16];
    #pragma unroll
    for (int j = 0; j < 16; ++j) h[j] = 0.f;
    float sdl = 0.f;
    const float nL2E = -L2E;

    if (fast) {
        for (int r = 0; r < CL; ++r) {
            unsigned u = sdxu[r][tid ^ r];
            float dl = __uint_as_float(u << 16);
            float xcv = __uint_as_float(u & 0xffff0000u);
            float Bv[16], Cv[16];
            #pragma unroll
            for (int k = 0; k < 4; ++k) {
                *(float4*)&Bv[k * 4] = *(const float4*)&sB[r][k * 4];
                *(float4*)&Cv[k * 4] = *(const float4*)&sC[r][k * 4];
            }
            float u0 = dl * xcv;
            sdl += dl;
            float e0 = __builtin_amdgcn_exp2f(dl * Avl[0]);
            float rr = __builtin_amdgcn_exp2f(dl * nL2E);
            float rr2 = rr * rr, rr4 = rr2 * rr2, rr8 = rr4 * rr4;
            float e[16];
            e[0] = e0;       e[1] = e0 * rr;
            e[2] = e0 * rr2; e[3] = e[1] * rr2;
            #pragma unroll
            for (int j = 0; j < 4; ++j) e[4 + j] = e[j] * rr4;
            #pragma unroll
            for (int j = 0; j < 8; ++j) e[8 + j] = e[j] * rr8;
            float t0 = 0.f, t1 = 0.f, t2 = 0.f, t3 = 0.f;
            #pragma unroll
            for (int j = 0; j < 4; ++j) {
                h[4*j+0] = fmaf(e[4*j+0], h[4*j+0], u0 * Bv[4*j+0]);
                h[4*j+1] = fmaf(e[4*j+1], h[4*j+1], u0 * Bv[4*j+1]);
                h[4*j+2] = fmaf(e[4*j+2], h[4*j+2], u0 * Bv[4*j+2]);
                h[4*j+3] = fmaf(e[4*j+3], h[4*j+3], u0 * Bv[4*j+3]);
                t0 = fmaf(h[4*j+0], Cv[4*j+0], t0);
                t1 = fmaf(h[4*j+1], Cv[4*j+1], t1);
                t2 = fmaf(h[4*j+2], Cv[4*j+2], t2);
                t3 = fmaf(h[4*j+3], Cv[4*j+3], t3);
            }
            float ts = (t0 + t1) + (t2 + t3);
            int lr = ch * CL + r;
            float yv = fmaf(xcv, Dv, ts);
            yls[((size_t)b * LL + lr) * DI + d] =
                (unsigned)f2bf(yv) | ((unsigned)f2bf(sdl) << 16);
        }
    } else {
        for (int r = 0; r < CL; ++r) {
            unsigned u = sdxu[r][tid ^ r];
            float dl = __uint_as_float(u << 16);
            float xcv = __uint_as_float(u & 0xffff0000u);
            float u0 = dl * xcv;
            sdl += dl;
            float ts = 0.f;
            #pragma unroll
            for (int j = 0; j < 16; ++j) {
                float e = __builtin_amdgcn_exp2f(dl * Avl[j]);
                h[j] = fmaf(e, h[j], u0 * sB[r][j]);
                ts = fmaf(h[j], sC[r][j], ts);
            }
            int lr = ch * CL + r;
            float yv = fmaf(xcv, Dv, ts);
            yls[((size_t)b * LL + lr) * DI + d] =
                (unsigned)f2bf(yv) | ((unsigned)f2bf(sdl) << 16);
        }
    }

    size_t base = (size_t)ch * PLANE + (size_t)(((dir * 4 + b) * DI + d) * DS2);
    float ac[16];
    #pragma unroll
    for (int j = 0; j < 16; ++j) ac[j] = __builtin_amdgcn_exp2f(Avl[j] * sdl);
    #pragma unroll
    for (int k = 0; k < 4; ++k) {
        *(float4*)&AC[base + k * 4] = *(const float4*)&ac[k * 4];
        *(float4*)&HC[base + k * 4] = *(const float4*)&h[k * 4];
    }
}

// ---------------- scan part2: sequential chunk combine --------------------
__global__ __launch_bounds__(256) void scan_part2(
    const float* __restrict__ AC, const float* __restrict__ HC,
    float* __restrict__ HIN) {
    int idx = blockIdx.x * 256 + threadIdx.x;
    float hin = 0.f;
    #pragma unroll
    for (int ch = 0; ch < NCH; ++ch) {
        size_t o = (size_t)ch * PLANE + idx;
        HIN[o] = hin;
        hin = fmaf(AC[o], hin, HC[o]);
    }
}

// ---------------- scan lite: parallel correction + gate -> ycat -----------
__global__ __launch_bounds__(256, 8) void scan_lite(
    const unsigned* __restrict__ yls0, const unsigned* __restrict__ yls1,
    const unsigned short* __restrict__ bc0, const unsigned short* __restrict__ bc1,
    const unsigned short* __restrict__ xz,
    const float* __restrict__ Al0, const float* __restrict__ Al1,
    const float* __restrict__ HIN, unsigned short* __restrict__ ycat) {
    int dir = blockIdx.z;
    const unsigned* yls         = dir ? yls1 : yls0;
    const unsigned short* bc    = dir ? bc1 : bc0;
    const float* Alog           = dir ? Al1 : Al0;
    int b = blockIdx.y >> 5, ch = blockIdx.y & 31;
    int d0 = blockIdx.x * 64;
    int tid = threadIdx.x;
    int dg = tid & 63, lg = tid >> 6;
    int d = d0 + dg;

    __shared__ unsigned sC[CL][8];
    {
        int row = tid >> 2, q = tid & 3;
        if (q < 2) {
            int lr = ch * CL + row;
            int l = dir ? (LL - 1 - lr) : lr;
            size_t t = (size_t)b * LL + l;
            uint4 cu = *(const uint4*)(bc + t * 32 + 16 + q * 8);
            *(uint4*)&sC[row][q * 4] = cu;
        }
    }
    __syncthreads();

    float Av[16];
    bool fastA = true;
    #pragma unroll
    for (int qq = 0; qq < 4; ++qq) {
        float4 Al = *(const float4*)&Alog[d * DS2 + qq * 4];
        Av[qq * 4 + 0] = -__expf(Al.x);
        Av[qq * 4 + 1] = -__expf(Al.y);
        Av[qq * 4 + 2] = -__expf(Al.z);
        Av[qq * 4 + 3] = -__expf(Al.w);
    }
    #pragma unroll
    for (int n = 0; n < 16; ++n)
        fastA = fastA && (fabsf(Av[n] + (float)(n + 1)) < 1e-3f * (float)(n + 1));

    float hin[16];
    size_t hbase = (size_t)ch * PLANE + (size_t)(((dir * 4 + b) * DI + d) * DS2);
    #pragma unroll
    for (int qq = 0; qq < 4; ++qq)
        *(float4*)&hin[qq * 4] = *(const float4*)&HIN[hbase + qq * 4];

    #pragma unroll 2
    for (int i = 0; i < 16; ++i) {
        int row = lg * 16 + i;
        int lr = ch * CL + row;
        int ll = dir ? (LL - 1 - lr) : lr;
        size_t tt = (size_t)b * LL + ll;
        unsigned u = yls[((size_t)b * LL + lr) * DI + d];
        float yv = __uint_as_float(u << 16);
        float s  = __uint_as_float(u & 0xffff0000u);
        if (fastA) {
            float E = __builtin_amdgcn_exp2f(-s * L2E);
            if (__any(E > 3e-6f)) {
                float acc = 0.f;
                #pragma unroll
                for (int p = 7; p >= 0; --p) {
                    unsigned cp = sC[row][p];
                    float C0 = __uint_as_float(cp << 16);
                    float C1 = __uint_as_float(cp & 0xffff0000u);
                    acc = fmaf(acc, E, C1 * hin[2 * p + 1]);
                    acc = fmaf(acc, E, C0 * hin[2 * p]);
                }
                yv = fmaf(acc, E, yv);
            }
        } else {
            float acc = 0.f;
            #pragma unroll
            for (int p = 0; p < 8; ++p) {
                unsigned cp = sC[row][p];
                float C0 = __uint_as_float(cp << 16);
                float C1 = __uint_as_float(cp & 0xffff0000u);
                float e0 = __builtin_amdgcn_exp2f(s * Av[2 * p] * L2E);
                float e1 = __builtin_amdgcn_exp2f(s * Av[2 * p + 1] * L2E);
                acc = fmaf(e0 * hin[2 * p], C0, acc);
                acc = fmaf(e1 * hin[2 * p + 1], C1, acc);
            }
            yv += acc;
        }
        float zz = bf2f(xz[tt * 2048 + (size_t)dir * 1024 + 512 + d]);
        yv *= zz / (1.f + __expf(-zz));
        ycat[tt * 1024 + (size_t)dir * 512 + d] = f2bf(yv);
    }
}

// -------------------------------------------------------------------------
extern "C" void kernel_launch(void* const* d_in, const int* in_sizes, int n_in,
                              void* d_out, int out_size, void* d_ws, size_t ws_size,
                              hipStream_t stream) {
    const float* x = (const float*)d_in[0];
    const float* p[2][10];
    for (int dir = 0; dir < 2; ++dir)
        for (int i = 0; i < 10; ++i)
            p[dir][i] = (const float*)d_in[1 + dir * 10 + i];
    // p[dir]: 0 norm, 1 in_proj, 2 conv_w, 3 conv_b, 4 x_proj,
    //         5 dt_w, 6 dt_b, 7 A_log, 8 D, 9 out_proj

    char* w = (char*)d_ws;
    auto alloc = [&](size_t bytes) { char* q = w; w += (bytes + 255) & ~(size_t)255; return q; };
    unsigned short* xn    = (unsigned short*)alloc((size_t)NTOK * DM * 2);
    unsigned short* w_in  = (unsigned short*)alloc((size_t)2048 * 256 * 2);
    unsigned short* w_p2  = (unsigned short*)alloc((size_t)1152 * 512 * 2);
    unsigned short* w_out = (unsigned short*)alloc((size_t)256 * 1024 * 2);
    unsigned short* xzcat = (unsigned short*)alloc((size_t)NTOK * 2048 * 2);
    unsigned short *xcb[2], *dlt[2], *bc[2];
    unsigned* yls[2];
    for (int dir = 0; dir < 2; ++dir) {
        xcb[dir] = (unsigned short*)alloc((size_t)NTOK * DI * 2);
        dlt[dir] = (unsigned short*)alloc((size_t)NTOK * DI * 2);
        bc[dir]  = (unsigned short*)alloc((size_t)NTOK * 32 * 2);
        yls[dir] = (unsigned*)alloc((size_t)NTOK * DI * 4);
    }
    unsigned short* ycat = (unsigned short*)alloc((size_t)NTOK * 1024 * 2);
    float* AC  = (float*)alloc((size_t)NCH * PLANE * 4);
    float* HC  = (float*)alloc((size_t)NCH * PLANE * 4);
    float* HIN = (float*)alloc((size_t)NCH * PLANE * 4);
    float* out = (float*)d_out;

    prep_kernel<<<3456 + NTOK, 256, 0, stream>>>(
        p[0][1], p[0][0], p[1][1], p[1][0],
        p[0][4], p[0][5], p[1][4], p[1][5],
        p[0][9], p[1][9], w_in, w_p2, w_out, x, xn);

    // in_proj: M=8192 N=2048 K=256, 512 blocks x 8 m-tiles
    mfma_gemm<EPI_IN, 256, 8><<<dim3(32, 16, 1), 256, 0, stream>>>(
        xn, xn, w_in, xzcat, nullptr, nullptr, nullptr,
        nullptr, nullptr, nullptr, nullptr);

    conv_silu_kernel<<<dim3(2048, 2), 256, 0, stream>>>(
        xzcat, p[0][2], p[1][2], p[0][3], p[1][3], xcb[0], xcb[1]);

    // proj2: M=8192 N=576 K=512, 576 blocks x 4 m-tiles (both dirs grid.z)
    mfma_gemm<EPI_P2, 512, 4><<<dim3(9, 32, 2), 256, 0, stream>>>(
        xcb[0], xcb[1], w_p2, dlt[0], dlt[1], bc[0], bc[1],
        p[0][6], p[1][6], nullptr, nullptr);

    scan_part1<<<dim3(DI / 128, 4 * NCH, 2), 128, 0, stream>>>(
        dlt[0], dlt[1], xcb[0], xcb[1], bc[0], bc[1], p[0][7], p[1][7],
        p[0][8], p[1][8], AC, HC, yls[0], yls[1]);
    scan_part2<<<PLANE / 256, 256, 0, stream>>>(AC, HC, HIN);
    scan_lite<<<dim3(DI / 64, 4 * NCH, 2), 256, 0, stream>>>(
        yls[0], yls[1], bc[0], bc[1], xzcat,
        p[0][7], p[1][7], HIN, ycat);

    // out_proj: M=8192 N=256 K=1024, 256 blocks x 2 m-tiles
    mfma_gemm<EPI_OUT, 1024, 2><<<dim3(4, 64, 1), 256, 0, stream>>>(
        ycat, ycat, w_out, nullptr, nullptr, nullptr, nullptr,
        nullptr, nullptr, x, out);
}

// Round 17
// 167.011 us; speedup vs baseline: 1.0841x; 1.0841x over previous
//
#include <hip/hip_runtime.h>
#include <hip/hip_bf16.h>
#include <math.h>

// Bidirectional Mamba block. Round 17: r15 base (best, 168.6us) +
// operand-swapped MFMA (mfma(W,A)): lane holds 4 consecutive n at fixed m
// -> packed uint2/float4 C-stores (64 scalar stores -> 16 vector per thread).
// r16's persistent m-loop reverted (cut TLP, -12us).

#define NTOK 8192
#define LL   2048
#define DM   256
#define DI   512
#define DS2  16
#define CL   64
#define NCH  32
#define PLANE 65536
#define KSTEP 64

typedef __bf16 bf16x8 __attribute__((ext_vector_type(8)));
typedef float f32x4 __attribute__((ext_vector_type(4)));

__device__ inline unsigned short f2bf(float f) {
    unsigned u = __float_as_uint(f);
    unsigned r = (u + 0x7fffu + ((u >> 16) & 1u)) >> 16;
    return (unsigned short)r;
}
__device__ inline float bf2f(unsigned short s) {
    return __uint_as_float((unsigned)s << 16);
}
__device__ inline unsigned pack2(float a, float b) {
    return (unsigned)f2bf(a) | ((unsigned)f2bf(b) << 16);
}

#define L2E 1.4426950408889634f
#define LN2 0.6931471805599453f

__device__ inline float softplus_fast(float x) {
    float e = __builtin_amdgcn_exp2f(-fabsf(x) * L2E);
    float l = __builtin_amdgcn_logf(1.f + e);
    return fmaxf(x, 0.f) + l * LN2;
}

// bijective XCD-chunk swizzle (m204)
__device__ inline int xcd_swz(int bid, int nwg) {
    int q = nwg >> 3, r = nwg & 7;
    int xcd = bid & 7, lo = bid >> 3;
    return (xcd < r ? xcd * (q + 1) : r * (q + 1) + (xcd - r) * q) + lo;
}

#define GLDS(gp, lp) __builtin_amdgcn_global_load_lds( \
    (const __attribute__((address_space(1))) void*)(gp), \
    (__attribute__((address_space(3))) void*)(lp), 16, 0, 0)

// ---------------- prep: weight conversion / folding + rmsnorm -------------
__global__ __launch_bounds__(256) void prep_kernel(
    const float* __restrict__ ip0, const float* __restrict__ nw0,
    const float* __restrict__ ip1, const float* __restrict__ nw1,
    const float* __restrict__ xp0, const float* __restrict__ dtw0,
    const float* __restrict__ xp1, const float* __restrict__ dtw1,
    const float* __restrict__ op0, const float* __restrict__ op1,
    unsigned short* __restrict__ w_in, unsigned short* __restrict__ w_p2,
    unsigned short* __restrict__ w_out,
    const float* __restrict__ x, unsigned short* __restrict__ xn) {
    int bid = blockIdx.x, tid = threadIdx.x;
    if (bid < 2048) {                       // in_proj rows, norm folded
        int dir = bid >> 10, n = bid & 1023;
        const float* ip = dir ? ip1 : ip0;
        const float* nw = dir ? nw1 : nw0;
        w_in[(size_t)bid * 256 + tid] = f2bf(ip[n * 256 + tid] * nw[tid]);
    } else if (bid < 3200) {                // w_p2 rows (576 per dir)
        int idx = bid - 2048;
        int dir = idx / 576, row = idx % 576;
        const float* xp = dir ? xp1 : xp0;
        const float* dtw = dir ? dtw1 : dtw0;
        unsigned short* dst = w_p2 + (size_t)idx * 512;
        for (int k = tid; k < 512; k += 256) {
            float v = 0.f;
            if (row < 512) {
                #pragma unroll
                for (int r = 0; r < 16; ++r) v = fmaf(dtw[row * 16 + r], xp[r * 512 + k], v);
            } else if (row < 544) {
                v = xp[(16 + row - 512) * 512 + k];
            }
            dst[k] = f2bf(v);
        }
    } else if (bid < 3456) {                // w_out rows (256), K=1024 concat
        int n = bid - 3200;
        for (int k = tid; k < 1024; k += 256) {
            float v = (k < 512) ? op0[n * 512 + k] : op1[n * 512 + (k - 512)];
            w_out[(size_t)n * 1024 + k] = f2bf(v);
        }
    } else {                                // rmsnorm token
        int t = bid - 3456;
        float v = x[(size_t)t * DM + tid];
        float ss = v * v;
        #pragma unroll
        for (int m = 1; m < 64; m <<= 1) ss += __shfl_xor(ss, m);
        __shared__ float ws[4];
        if ((tid & 63) == 0) ws[tid >> 6] = ss;
        __syncthreads();
        float tot = ws[0] + ws[1] + ws[2] + ws[3];
        float scale = rsqrtf(tot / (float)DM + 1e-5f);
        xn[(size_t)t * DM + tid] = f2bf(v * scale);
    }
}

// ---------------- bf16 MFMA GEMM: C = A[M,K] @ W[N,K]^T -------------------
// r10/r15 structure; MFMA operands swapped => lane holds 4 consecutive n at
// fixed m => packed vector C-stores.
#define EPI_IN  0   // -> xzcat[m][n], n in [0,2048)
#define EPI_P2  1
#define EPI_OUT 2

template <int EPI>
__global__ __launch_bounds__(256) void mfma_gemm(
    const unsigned short* __restrict__ A0, const unsigned short* __restrict__ A1,
    const unsigned short* __restrict__ Wb, int K,
    unsigned short* __restrict__ d0, unsigned short* __restrict__ d1,
    unsigned short* __restrict__ e0, unsigned short* __restrict__ e1,
    const float* __restrict__ aux0, const float* __restrict__ aux1,
    const float* __restrict__ Xres, float* __restrict__ outF) {
    __shared__ char lds[2][2][8192];     // [buf][A/B][64 rows * 128B]
    int tid = threadIdx.x;
    int lane = tid & 63, wid = tid >> 6;
    int wm = wid >> 1, wn = wid & 1;
    int nwg = gridDim.x * gridDim.y;
    int lid = xcd_swz(blockIdx.y * gridDim.x + blockIdx.x, nwg);
    int n0 = (lid % gridDim.x) * 64;
    int m0 = (lid / gridDim.x) * 64;
    int dir = blockIdx.z;
    const unsigned short* A = dir ? A1 : A0;
    const unsigned short* W = Wb + ((EPI == EPI_P2) ? (size_t)dir * 576 * 512 : 0);

    const int s1 = tid, s2 = tid + 256;
    const int r1 = s1 >> 3, c1 = (s1 & 7) ^ (r1 & 7);
    const int r2 = s2 >> 3, c2 = (s2 & 7) ^ (r2 & 7);

    f32x4 acc[2][2] = {};
    int nt = K / KSTEP;

    auto stage = [&](int t, int buf) {
        int k0 = t * KSTEP;
        GLDS(A + (size_t)(m0 + r1) * K + k0 + c1 * 8, &lds[buf][0][0] + wid * 1024);
        GLDS(A + (size_t)(m0 + r2) * K + k0 + c2 * 8, &lds[buf][0][0] + 4096 + wid * 1024);
        GLDS(W + (size_t)(n0 + r1) * K + k0 + c1 * 8, &lds[buf][1][0] + wid * 1024);
        GLDS(W + (size_t)(n0 + r2) * K + k0 + c2 * 8, &lds[buf][1][0] + 4096 + wid * 1024);
    };

    stage(0, 0);
    for (int t = 0; t < nt; ++t) {
        int buf = t & 1;
        __syncthreads();
        if (t + 1 < nt) stage(t + 1, buf ^ 1);
        const char* Ab = &lds[buf][0][0];
        const char* Bb = &lds[buf][1][0];
        bf16x8 af[2][2], bfv[2][2];
        #pragma unroll
        for (int mf = 0; mf < 2; ++mf)
            #pragma unroll
            for (int kf = 0; kf < 2; ++kf) {
                int r = wm * 32 + mf * 16 + (lane & 15);
                int c = (lane >> 4) + kf * 4;
                af[mf][kf] = *(const bf16x8*)(Ab + r * 128 + ((c ^ (r & 7)) << 4));
            }
        #pragma unroll
        for (int nf = 0; nf < 2; ++nf)
            #pragma unroll
            for (int kf = 0; kf < 2; ++kf) {
                int r = wn * 32 + nf * 16 + (lane & 15);
                int c = (lane >> 4) + kf * 4;
                bfv[nf][kf] = *(const bf16x8*)(Bb + r * 128 + ((c ^ (r & 7)) << 4));
            }
        // swapped operands: D^T fragment — lane: m = lane&15, n = (lane>>4)*4+r
        #pragma unroll
        for (int kf = 0; kf < 2; ++kf)
            #pragma unroll
            for (int mf = 0; mf < 2; ++mf)
                #pragma unroll
                for (int nf = 0; nf < 2; ++nf)
                    acc[mf][nf] = __builtin_amdgcn_mfma_f32_16x16x32_bf16(
                        bfv[nf][kf], af[mf][kf], acc[mf][nf], 0, 0, 0);
    }

    int mb0 = m0 + wm * 32 + (lane & 15);          // fixed m per lane
    int nb0 = n0 + wn * 32 + ((lane >> 4) << 2);   // 4 consecutive n per frag
    #pragma unroll
    for (int mf = 0; mf < 2; ++mf)
        #pragma unroll
        for (int nf = 0; nf < 2; ++nf) {
            int m = mb0 + mf * 16;
            int n = nb0 + nf * 16;
            float v0 = acc[mf][nf][0], v1 = acc[mf][nf][1];
            float v2 = acc[mf][nf][2], v3 = acc[mf][nf][3];
            if (EPI == EPI_IN) {
                uint2 pk = make_uint2(pack2(v0, v1), pack2(v2, v3));
                *(uint2*)(d0 + (size_t)m * 2048 + n) = pk;
            } else if (EPI == EPI_P2) {
                const float* aux = dir ? aux1 : aux0;
                if (n < 512) {
                    float s0 = softplus_fast(v0 + aux[n]);
                    float s1 = softplus_fast(v1 + aux[n + 1]);
                    float s2 = softplus_fast(v2 + aux[n + 2]);
                    float s3 = softplus_fast(v3 + aux[n + 3]);
                    uint2 pk = make_uint2(pack2(s0, s1), pack2(s2, s3));
                    *(uint2*)((dir ? d1 : d0) + (size_t)m * 512 + n) = pk;
                } else if (n < 544) {
                    uint2 pk = make_uint2(pack2(v0, v1), pack2(v2, v3));
                    *(uint2*)((dir ? e1 : e0) + (size_t)m * 32 + (n - 512)) = pk;
                }
            } else {
                float4 xr = *(const float4*)&Xres[(size_t)m * 256 + n];
                float4 o = make_float4(v0 + 2.f * xr.x, v1 + 2.f * xr.y,
                                       v2 + 2.f * xr.z, v3 + 2.f * xr.w);
                *(float4*)&outF[(size_t)m * 256 + n] = o;
            }
        }
}

// ---------------- depthwise conv4 + silu (bf16, 8 ch/thread) --------------
__global__ __launch_bounds__(256) void conv_silu_kernel(
    const unsigned short* __restrict__ xz,
    const float* __restrict__ cw0, const float* __restrict__ cw1,
    const float* __restrict__ cb0, const float* __restrict__ cb1,
    unsigned short* __restrict__ o0, unsigned short* __restrict__ o1) {
    int dir = blockIdx.y;
    const float* cw = dir ? cw1 : cw0;
    const float* cb = dir ? cb1 : cb0;
    unsigned short* xc = dir ? o1 : o0;
    int idx8 = blockIdx.x * 256 + threadIdx.x;
    int t = idx8 >> 6;
    int c8 = (idx8 & 63) << 3;
    int l = t & (LL - 1);
    const unsigned short* xh = xz + (size_t)dir * 1024 + c8;

    float wreg[32];
    #pragma unroll
    for (int q = 0; q < 8; ++q)
        *(float4*)&wreg[q * 4] = *(const float4*)&cw[c8 * 4 + q * 4];
    float acc[8];
    *(float4*)&acc[0] = *(const float4*)&cb[c8];
    *(float4*)&acc[4] = *(const float4*)&cb[c8 + 4];

    #pragma unroll
    for (int k = 0; k < 4; ++k) {
        int lo = dir ? (l + 3 - k) : (l - 3 + k);
        if (lo < 0 || lo >= LL) continue;
        uint4 u = *(const uint4*)(xh + (size_t)(t + lo - l) * 2048);
        unsigned wv[4] = {u.x, u.y, u.z, u.w};
        #pragma unroll
        for (int j = 0; j < 4; ++j) {
            float flo = __uint_as_float(wv[j] << 16);
            float fhi = __uint_as_float(wv[j] & 0xffff0000u);
            acc[2 * j]     = fmaf(flo, wreg[(2 * j) * 4 + k], acc[2 * j]);
            acc[2 * j + 1] = fmaf(fhi, wreg[(2 * j + 1) * 4 + k], acc[2 * j + 1]);
        }
    }
    unsigned out[4];
    #pragma unroll
    for (int j = 0; j < 4; ++j) {
        float a0 = acc[2 * j], a1 = acc[2 * j + 1];
        float s0 = a0 / (1.f + __expf(-a0));
        float s1 = a1 / (1.f + __expf(-a1));
        out[j] = (unsigned)f2bf(s0) | ((unsigned)f2bf(s1) << 16);
    }
    *(uint4*)(xc + (size_t)idx8 * 8) = make_uint4(out[0], out[1], out[2], out[3]);
}

// ---------------- scan part1: local chunk scan -> AC, HC, (y_loc,s) -------
// 128 threads, each owns one d with all 16 n-states (no shuffle). (r15)
__global__ __launch_bounds__(128, 2) void scan_part1(
    const unsigned short* __restrict__ dlt0, const unsigned short* __restrict__ dlt1,
    const unsigned short* __restrict__ xc0, const unsigned short* __restrict__ xc1,
    const unsigned short* __restrict__ bc0, const unsigned short* __restrict__ bc1,
    const float* __restrict__ Al0, const float* __restrict__ Al1,
    const float* __restrict__ Dp0, const float* __restrict__ Dp1,
    float* __restrict__ AC, float* __restrict__ HC,
    unsigned* __restrict__ yls0, unsigned* __restrict__ yls1) {
    int dir = blockIdx.z;
    const unsigned short* delta = dir ? dlt1 : dlt0;
    const unsigned short* xc    = dir ? xc1 : xc0;
    const unsigned short* bc    = dir ? bc1 : bc0;
    const float* Alog           = dir ? Al1 : Al0;
    const float* Dp             = dir ? Dp1 : Dp0;
    unsigned* yls               = dir ? yls1 : yls0;
    int b = blockIdx.y >> 5, ch = blockIdx.y & 31;
    int d0 = blockIdx.x * 128;
    int tid = threadIdx.x;               // 0..127 == local d
    int d = d0 + tid;

    __shared__ unsigned sdxu[CL][128];   // [l][d] packed (delta|xc), col XOR row
    __shared__ float sB[CL][16];         // [l][n] f32
    __shared__ float sC[CL][16];
    {
        int row = tid >> 1, q2 = tid & 1;
        int lr = ch * CL + row;
        int l = dir ? (LL - 1 - lr) : lr;
        size_t t = (size_t)b * LL + l;
        const uint4* dp = (const uint4*)(delta + t * DI + d0) + q2 * 8;
        const uint4* xp = (const uint4*)(xc + t * DI + d0) + q2 * 8;
        #pragma unroll
        for (int hh = 0; hh < 8; ++hh) {
            uint4 du = dp[hh], xu = xp[hh];
            unsigned dw[4] = {du.x, du.y, du.z, du.w};
            unsigned xw[4] = {xu.x, xu.y, xu.z, xu.w};
            #pragma unroll
            for (int j = 0; j < 4; ++j) {
                int col = q2 * 64 + hh * 8 + 2 * j;
                sdxu[row][col ^ row]       = (dw[j] & 0xffffu) | (xw[j] << 16);
                sdxu[row][(col + 1) ^ row] = (dw[j] >> 16) | (xw[j] & 0xffff0000u);
            }
        }
        uint4 Bu = *(const uint4*)(bc + t * 32 + q2 * 8);
        uint4 Cu = *(const uint4*)(bc + t * 32 + 16 + q2 * 8);
        unsigned bw[4] = {Bu.x, Bu.y, Bu.z, Bu.w};
        unsigned cw[4] = {Cu.x, Cu.y, Cu.z, Cu.w};
        #pragma unroll
        for (int j = 0; j < 4; ++j) {
            sB[row][q2 * 8 + 2 * j]     = __uint_as_float(bw[j] << 16);
            sB[row][q2 * 8 + 2 * j + 1] = __uint_as_float(bw[j] & 0xffff0000u);
            sC[row][q2 * 8 + 2 * j]     = __uint_as_float(cw[j] << 16);
            sC[row][q2 * 8 + 2 * j + 1] = __uint_as_float(cw[j] & 0xffff0000u);
        }
    }
    __syncthreads();

    float Av[16], Avl[16];
    #pragma unroll
    for (int qq = 0; qq < 4; ++qq) {
        float4 Al = *(const float4*)&Alog[d * DS2 + qq * 4];
        Av[qq * 4 + 0] = -__expf(Al.x);
        Av[qq * 4 + 1] = -__expf(Al.y);
        Av[qq * 4 + 2] = -__expf(Al.z);
        Av[qq * 4 + 3] = -__expf(Al.w);
    }
    #pragma unroll
    for (int j = 0; j < 16; ++j) Avl[j] = Av[j] * L2E;
    bool fast = true;
    #pragma unroll
    for (int j = 0; j < 15; ++j)
        fast = fast && (fabsf(Av[j + 1] - Av[j] + 1.f) < 1e-2f);

    float Dv = Dp[d];
    float h[16];
    #pragma unroll
    for (int j = 0; j < 16; ++j) h[j] = 0.f;
    float sdl = 0.f;
    const float nL2E = -L2E;

    if (fast) {
        for (int r = 0; r < CL; ++r) {
            unsigned u = sdxu[r][tid ^ r];
            float dl = __uint_as_float(u << 16);
            float xcv = __uint_as_float(u & 0xffff0000u);
            float Bv[16], Cv[16];
            #pragma unroll
            for (int k = 0; k < 4; ++k) {
                *(float4*)&Bv[k * 4] = *(const float4*)&sB[r][k * 4];
                *(float4*)&Cv[k * 4] = *(const float4*)&sC[r][k * 4];
            }
            float u0 = dl * xcv;
            sdl += dl;
            float e0 = __builtin_amdgcn_exp2f(dl * Avl[0]);
            float rr = __builtin_amdgcn_exp2f(dl * nL2E);
            float rr2 = rr * rr, rr4 = rr2 * rr2, rr8 = rr4 * rr4;
            float e[16];
            e[0] = e0;       e[1] = e0 * rr;
            e[2] = e0 * rr2; e[3] = e[1] * rr2;
            #pragma unroll
            for (int j = 0; j < 4; ++j) e[4 + j] = e[j] * rr4;
            #pragma unroll
            for (int j = 0; j < 8; ++j) e[8 + j] = e[j] * rr8;
            float t0 = 0.f, t1 = 0.f, t2 = 0.f, t3 = 0.f;
            #pragma unroll
            for (int j = 0; j < 4; ++j) {
                h[4*j+0] = fmaf(e[4*j+0], h[4*j+0], u0 * Bv[4*j+0]);
                h[4*j+1] = fmaf(e[4*j+1], h[4*j+1], u0 * Bv[4*j+1]);
                h[4*j+2] = fmaf(e[4*j+2], h[4*j+2], u0 * Bv[4*j+2]);
                h[4*j+3] = fmaf(e[4*j+3], h[4*j+3], u0 * Bv[4*j+3]);
                t0 = fmaf(h[4*j+0], Cv[4*j+0], t0);
                t1 = fmaf(h[4*j+1], Cv[4*j+1], t1);
                t2 = fmaf(h[4*j+2], Cv[4*j+2], t2);
                t3 = fmaf(h[4*j+3], Cv[4*j+3], t3);
            }
            float ts = (t0 + t1) + (t2 + t3);
            int lr = ch * CL + r;
            float yv = fmaf(xcv, Dv, ts);
            yls[((size_t)b * LL + lr) * DI + d] =
                (unsigned)f2bf(yv) | ((unsigned)f2bf(sdl) << 16);
        }
    } else {
        for (int r = 0; r < CL; ++r) {
            unsigned u = sdxu[r][tid ^ r];
            float dl = __uint_as_float(u << 16);
            float xcv = __uint_as_float(u & 0xffff0000u);
            float u0 = dl * xcv;
            sdl += dl;
            float ts = 0.f;
            #pragma unroll
            for (int j = 0; j < 16; ++j) {
                float e = __builtin_amdgcn_exp2f(dl * Avl[j]);
                h[j] = fmaf(e, h[j], u0 * sB[r][j]);
                ts = fmaf(h[j], sC[r][j], ts);
            }
            int lr = ch * CL + r;
            float yv = fmaf(xcv, Dv, ts);
            yls[((size_t)b * LL + lr) * DI + d] =
                (unsigned)f2bf(yv) | ((unsigned)f2bf(sdl) << 16);
        }
    }

    size_t base = (size_t)ch * PLANE + (size_t)(((dir * 4 + b) * DI + d) * DS2);
    float ac[16];
    #pragma unroll
    for (int j = 0; j < 16; ++j) ac[j] = __builtin_amdgcn_exp2f(Avl[j] * sdl);
    #pragma unroll
    for (int k = 0; k < 4; ++k) {
        *(float4*)&AC[base + k * 4] = *(const float4*)&ac[k * 4];
        *(float4*)&HC[base + k * 4] = *(const float4*)&h[k * 4];
    }
}

// ---------------- scan part2: sequential chunk combine --------------------
__global__ __launch_bounds__(256) void scan_part2(
    const float* __restrict__ AC, const float* __restrict__ HC,
    float* __restrict__ HIN) {
    int idx = blockIdx.x * 256 + threadIdx.x;
    float hin = 0.f;
    #pragma unroll
    for (int ch = 0; ch < NCH; ++ch) {
        size_t o = (size_t)ch * PLANE + idx;
        HIN[o] = hin;
        hin = fmaf(AC[o], hin, HC[o]);
    }
}

// ---------------- scan lite: parallel correction + gate -> ycat -----------
__global__ __launch_bounds__(256, 8) void scan_lite(
    const unsigned* __restrict__ yls0, const unsigned* __restrict__ yls1,
    const unsigned short* __restrict__ bc0, const unsigned short* __restrict__ bc1,
    const unsigned short* __restrict__ xz,
    const float* __restrict__ Al0, const float* __restrict__ Al1,
    const float* __restrict__ HIN, unsigned short* __restrict__ ycat) {
    int dir = blockIdx.z;
    const unsigned* yls         = dir ? yls1 : yls0;
    const unsigned short* bc    = dir ? bc1 : bc0;
    const float* Alog           = dir ? Al1 : Al0;
    int b = blockIdx.y >> 5, ch = blockIdx.y & 31;
    int d0 = blockIdx.x * 64;
    int tid = threadIdx.x;
    int dg = tid & 63, lg = tid >> 6;
    int d = d0 + dg;

    __shared__ unsigned sC[CL][8];
    {
        int row = tid >> 2, q = tid & 3;
        if (q < 2) {
            int lr = ch * CL + row;
            int l = dir ? (LL - 1 - lr) : lr;
            size_t t = (size_t)b * LL + l;
            uint4 cu = *(const uint4*)(bc + t * 32 + 16 + q * 8);
            *(uint4*)&sC[row][q * 4] = cu;
        }
    }
    __syncthreads();

    float Av[16];
    bool fastA = true;
    #pragma unroll
    for (int qq = 0; qq < 4; ++qq) {
        float4 Al = *(const float4*)&Alog[d * DS2 + qq * 4];
        Av[qq * 4 + 0] = -__expf(Al.x);
        Av[qq * 4 + 1] = -__expf(Al.y);
        Av[qq * 4 + 2] = -__expf(Al.z);
        Av[qq * 4 + 3] = -__expf(Al.w);
    }
    #pragma unroll
    for (int n = 0; n < 16; ++n)
        fastA = fastA && (fabsf(Av[n] + (float)(n + 1)) < 1e-3f * (float)(n + 1));

    float hin[16];
    size_t hbase = (size_t)ch * PLANE + (size_t)(((dir * 4 + b) * DI + d) * DS2);
    #pragma unroll
    for (int qq = 0; qq < 4; ++qq)
        *(float4*)&hin[qq * 4] = *(const float4*)&HIN[hbase + qq * 4];

    #pragma unroll 2
    for (int i = 0; i < 16; ++i) {
        int row = lg * 16 + i;
        int lr = ch * CL + row;
        int ll = dir ? (LL - 1 - lr) : lr;
        size_t tt = (size_t)b * LL + ll;
        unsigned u = yls[((size_t)b * LL + lr) * DI + d];
        float yv = __uint_as_float(u << 16);
        float s  = __uint_as_float(u & 0xffff0000u);
        if (fastA) {
            float E = __builtin_amdgcn_exp2f(-s * L2E);
            if (__any(E > 3e-6f)) {
                float acc = 0.f;
                #pragma unroll
                for (int p = 7; p >= 0; --p) {
                    unsigned cp = sC[row][p];
                    float C0 = __uint_as_float(cp << 16);
                    float C1 = __uint_as_float(cp & 0xffff0000u);
                    acc = fmaf(acc, E, C1 * hin[2 * p + 1]);
                    acc = fmaf(acc, E, C0 * hin[2 * p]);
                }
                yv = fmaf(acc, E, yv);
            }
        } else {
            float acc = 0.f;
            #pragma unroll
            for (int p = 0; p < 8; ++p) {
                unsigned cp = sC[row][p];
                float C0 = __uint_as_float(cp << 16);
                float C1 = __uint_as_float(cp & 0xffff0000u);
                float e0 = __builtin_amdgcn_exp2f(s * Av[2 * p] * L2E);
                float e1 = __builtin_amdgcn_exp2f(s * Av[2 * p + 1] * L2E);
                acc = fmaf(e0 * hin[2 * p], C0, acc);
                acc = fmaf(e1 * hin[2 * p + 1], C1, acc);
            }
            yv += acc;
        }
        float zz = bf2f(xz[tt * 2048 + (size_t)dir * 1024 + 512 + d]);
        yv *= zz / (1.f + __expf(-zz));
        ycat[tt * 1024 + (size_t)dir * 512 + d] = f2bf(yv);
    }
}

// -------------------------------------------------------------------------
extern "C" void kernel_launch(void* const* d_in, const int* in_sizes, int n_in,
                              void* d_out, int out_size, void* d_ws, size_t ws_size,
                              hipStream_t stream) {
    const float* x = (const float*)d_in[0];
    const float* p[2][10];
    for (int dir = 0; dir < 2; ++dir)
        for (int i = 0; i < 10; ++i)
            p[dir][i] = (const float*)d_in[1 + dir * 10 + i];
    // p[dir]: 0 norm, 1 in_proj, 2 conv_w, 3 conv_b, 4 x_proj,
    //         5 dt_w, 6 dt_b, 7 A_log, 8 D, 9 out_proj

    char* w = (char*)d_ws;
    auto alloc = [&](size_t bytes) { char* q = w; w += (bytes + 255) & ~(size_t)255; return q; };
    unsigned short* xn    = (unsigned short*)alloc((size_t)NTOK * DM * 2);
    unsigned short* w_in  = (unsigned short*)alloc((size_t)2048 * 256 * 2);
    unsigned short* w_p2  = (unsigned short*)alloc((size_t)1152 * 512 * 2);
    unsigned short* w_out = (unsigned short*)alloc((size_t)256 * 1024 * 2);
    unsigned short* xzcat = (unsigned short*)alloc((size_t)NTOK * 2048 * 2);
    unsigned short *xcb[2], *dlt[2], *bc[2];
    unsigned* yls[2];
    for (int dir = 0; dir < 2; ++dir) {
        xcb[dir] = (unsigned short*)alloc((size_t)NTOK * DI * 2);
        dlt[dir] = (unsigned short*)alloc((size_t)NTOK * DI * 2);
        bc[dir]  = (unsigned short*)alloc((size_t)NTOK * 32 * 2);
        yls[dir] = (unsigned*)alloc((size_t)NTOK * DI * 4);
    }
    unsigned short* ycat = (unsigned short*)alloc((size_t)NTOK * 1024 * 2);
    float* AC  = (float*)alloc((size_t)NCH * PLANE * 4);
    float* HC  = (float*)alloc((size_t)NCH * PLANE * 4);
    float* HIN = (float*)alloc((size_t)NCH * PLANE * 4);
    float* out = (float*)d_out;

    prep_kernel<<<3456 + NTOK, 256, 0, stream>>>(
        p[0][1], p[0][0], p[1][1], p[1][0],
        p[0][4], p[0][5], p[1][4], p[1][5],
        p[0][9], p[1][9], w_in, w_p2, w_out, x, xn);

    // in_proj both dirs -> xzcat[m][2048]   (M=8192, N=2048, K=256)
    mfma_gemm<EPI_IN><<<dim3(32, 128, 1), 256, 0, stream>>>(
        xn, xn, w_in, 256, xzcat, nullptr, nullptr, nullptr,
        nullptr, nullptr, nullptr, nullptr);

    conv_silu_kernel<<<dim3(2048, 2), 256, 0, stream>>>(
        xzcat, p[0][2], p[1][2], p[0][3], p[1][3], xcb[0], xcb[1]);

    // proj2 (M=8192, N=576, K=512), both dirs via grid.z
    mfma_gemm<EPI_P2><<<dim3(9, 128, 2), 256, 0, stream>>>(
        xcb[0], xcb[1], w_p2, 512, dlt[0], dlt[1], bc[0], bc[1],
        p[0][6], p[1][6], nullptr, nullptr);

    scan_part1<<<dim3(DI / 128, 4 * NCH, 2), 128, 0, stream>>>(
        dlt[0], dlt[1], xcb[0], xcb[1], bc[0], bc[1], p[0][7], p[1][7],
        p[0][8], p[1][8], AC, HC, yls[0], yls[1]);
    scan_part2<<<PLANE / 256, 256, 0, stream>>>(AC, HC, HIN);
    scan_lite<<<dim3(DI / 64, 4 * NCH, 2), 256, 0, stream>>>(
        yls[0], yls[1], bc[0], bc[1], xzcat,
        p[0][7], p[1][7], HIN, ycat);

    // out_proj (M=8192, N=256, K=1024), out = acc + 2x
    mfma_gemm<EPI_OUT><<<dim3(4, 128, 1), 256, 0, stream>>>(
        ycat, ycat, w_out, 1024, nullptr, nullptr, nullptr, nullptr,
        nullptr, nullptr, x, out);
}